// Round 13
// baseline (245.640 us; speedup 1.0000x reference)
//
#include <hip/hip_runtime.h>

#define DD 1280
#define SS 2048
#define HH 20

typedef __bf16 bf16x8 __attribute__((ext_vector_type(8)));
typedef float f32x4 __attribute__((ext_vector_type(4)));

typedef __attribute__((address_space(3))) unsigned int lds_uint;
typedef __attribute__((address_space(1))) unsigned int glb_uint;
#define GLL16(g, l) __builtin_amdgcn_global_load_lds((const glb_uint*)(g), (lds_uint*)(l), 16, 0, 0)

__device__ __forceinline__ unsigned short f2bf(float f) {
  union { float f; unsigned u; } v; v.f = f;
  unsigned r = v.u + 0x7fffu + ((v.u >> 16) & 1u);
  return (unsigned short)(r >> 16);
}
__device__ __forceinline__ unsigned f2u(float f) {
  union { float f; unsigned u; } v; v.f = f; return v.u;
}
__device__ __forceinline__ unsigned pk2(float lo, float hi) {
  return ((unsigned)f2bf(hi) << 16) | (unsigned)f2bf(lo);
}

// ---- prep v3 (frozen; r12 closed the prep line: prep is ~15-20us, the rest
// of the non-kernel time is fixed harness overhead — two opposite rewrites
// were time-invariant) ----
__global__ __launch_bounds__(256) void prep_kernel(
    const float* __restrict__ X, const float* __restrict__ Wq,
    const float* __restrict__ Wk, const float* __restrict__ Wv,
    unsigned short* __restrict__ Xb, unsigned short* __restrict__ WT,
    float2* __restrict__ cs) {
  __shared__ __align__(8) unsigned short tile[64][68];
  int bid = blockIdx.x, tid = threadIdx.x;
  if (bid < 320) {
#pragma unroll
    for (int it = 0; it < 8; it++) {
      size_t base = (size_t)(it * 320 + bid) * 2048 + (size_t)tid * 8;
      const float4* xin = (const float4*)(X + base);
      float4 a = xin[0], c = xin[1];
      uint4 o = make_uint4(pk2(a.x, a.y), pk2(a.z, a.w), pk2(c.x, c.y), pk2(c.z, c.w));
      *(uint4*)(Xb + base) = o;
    }
  } else if (bid < 1520) {
    int wb = bid - 320;           // 3 * 400 tiles of 64x64
    int mat = wb / 400;
    int t = wb % 400;
    int tn = t % 20, tk = t / 20;
    const float* W = (mat == 0) ? Wq : ((mat == 1) ? Wk : Wv);
    int k0 = tk * 64, n0 = tn * 64;
    int r = tid >> 2, cq = tid & 3;   // 256 threads = 64 rows x 4 col-chunks(16)
    const float* src = W + (size_t)(k0 + r) * DD + n0 + cq * 16;
#pragma unroll
    for (int j = 0; j < 4; j++) {
      float4 wv = *(const float4*)(src + j * 4);
      *(ushort4*)&tile[r][cq * 16 + j * 4] =
          make_ushort4(f2bf(wv.x), f2bf(wv.y), f2bf(wv.z), f2bf(wv.w));
    }
    __syncthreads();
    unsigned short* out = WT + (size_t)mat * DD * DD + (size_t)(n0 + r) * DD + k0 + cq * 16;
#pragma unroll
    for (int j = 0; j < 4; j++) {
      ushort4 o = make_ushort4(tile[cq * 16 + j * 4 + 0][r], tile[cq * 16 + j * 4 + 1][r],
                               tile[cq * 16 + j * 4 + 2][r], tile[cq * 16 + j * 4 + 3][r]);
      *(ushort4*)(out + j * 4) = o;
    }
  } else {
    // rotary table: cs[sp][j] = (cos, sin)(sp * 10000^(-j/32)), 2048 x 32
#pragma unroll
    for (int it = 0; it < 4; it++) {
      int idx = (bid - 1520) * 1024 + it * 256 + tid;   // 64 blocks -> 65536 entries
      int sp = idx >> 5, j = idx & 31;
      float invf = exp2f(-(float)j * 0.41524101186092034f);
      float ang = (float)sp * invf;
      cs[idx] = make_float2(cosf(ang), sinf(ang));
    }
  }
}

// ---- QKV GEMM: m97/BK=32 structure + T1 XCD-chunked swizzle (frozen, ~69us) ----
__global__ __launch_bounds__(256) void qkv_gemm_kernel(
    const unsigned short* __restrict__ Xb, const unsigned short* __restrict__ WT,
    const float* __restrict__ bq, const float* __restrict__ bk, const float* __restrict__ bv,
    const float2* __restrict__ cs,
    unsigned short* __restrict__ Qr, unsigned short* __restrict__ Kr,
    unsigned short* __restrict__ VT) {
  __shared__ __align__(16) unsigned short As[128 * 32];
  __shared__ __align__(16) unsigned short Bs[128 * 32];
  int bx0 = blockIdx.x;           // 960 = 8 XCDs * 120
  int bx = (bx0 & 7) * 120 + (bx0 >> 3);   // XCD c works contiguous [c*120, c*120+120)
  int mat = bx / 320;
  int r0 = bx % 320;
  int tm = r0 / 10, tn = r0 % 10;
  int m0 = tm * 128, n0 = tn * 128;
  int tid = threadIdx.x;
  int lane = tid & 63, wave = tid >> 6;
  int c15 = lane & 15, quad = lane >> 4;
  int wm = wave >> 1, wn = wave & 1;
  const unsigned short* Wm = WT + (size_t)mat * DD * DD;

  int rowA = tid >> 2;
  int c8 = (tid & 3) * 8;
  const unsigned short* gA0 = Xb + (size_t)(m0 + rowA) * DD + c8;
  const unsigned short* gA1 = gA0 + (size_t)64 * DD;
  const unsigned short* gB0 = Wm + (size_t)(n0 + rowA) * DD + c8;
  const unsigned short* gB1 = gB0 + (size_t)64 * DD;
  unsigned short* ldsA0 = As + wave * 512;          // rows 0..63
  unsigned short* ldsA1 = As + 2048 + wave * 512;   // rows 64..127
  unsigned short* ldsB0 = Bs + wave * 512;
  unsigned short* ldsB1 = Bs + 2048 + wave * 512;

  f32x4 acc[4][4] = {};

  for (int kk = 0; kk < DD; kk += 32) {
    __syncthreads();
    GLL16(gA0 + kk, ldsA0);
    GLL16(gA1 + kk, ldsA1);
    GLL16(gB0 + kk, ldsB0);
    GLL16(gB1 + kk, ldsB1);
    __syncthreads();
    bf16x8 af[4];
#pragma unroll
    for (int mi = 0; mi < 4; mi++)
      af[mi] = *(const bf16x8*)(As + (wm * 64 + mi * 16 + c15) * 32 + quad * 8);
#pragma unroll
    for (int ni = 0; ni < 4; ni++) {
      bf16x8 bfr = *(const bf16x8*)(Bs + (wn * 64 + ni * 16 + c15) * 32 + quad * 8);
#pragma unroll
      for (int mi = 0; mi < 4; mi++)
        acc[mi][ni] = __builtin_amdgcn_mfma_f32_16x16x32_bf16(af[mi], bfr, acc[mi][ni], 0, 0, 0);
    }
  }

  int growb = m0 + wm * 64;
  int gcolb = n0 + wn * 64;
  if (mat == 2) {
    // V: write transposed VT[(b*H+h)*64+d][s]
#pragma unroll
    for (int mi = 0; mi < 4; mi++) {
      int row0 = growb + mi * 16 + quad * 4;
      int bb_ = row0 >> 11, sp = row0 & 2047;
#pragma unroll
      for (int ni = 0; ni < 4; ni++) {
        int gcol = gcolb + ni * 16 + c15;
        float bias = bv[gcol];
        int hh = gcol >> 6, dd = gcol & 63;
        f32x4 v = acc[mi][ni];
        ushort4 o = make_ushort4(f2bf(v[0] + bias), f2bf(v[1] + bias),
                                 f2bf(v[2] + bias), f2bf(v[3] + bias));
        *(ushort4*)(VT + ((size_t)((bb_ * HH + hh) * 64 + dd)) * SS + sp) = o;
      }
    }
  } else {
    // Q / K: bias + rotary via cs table
    unsigned short* Out = (mat == 0) ? Qr : Kr;
    const float* bias = (mat == 0) ? bq : bk;
    float qs = (mat == 0) ? 0.18033688011112042f : 1.0f;  // 0.125*log2(e) for Q
#pragma unroll
    for (int mi = 0; mi < 4; mi++) {
      int row0 = growb + mi * 16 + quad * 4;
#pragma unroll
      for (int ni = 0; ni < 2; ni++) {
        int gcol_lo = gcolb + ni * 16 + c15;      // d in [0,32) within head
        int gcol_hi = gcol_lo + 32;
        float blo = bias[gcol_lo], bhi = bias[gcol_hi];
        int d = ni * 16 + c15;
        f32x4 lo = acc[mi][ni], hi = acc[mi][ni + 2];
#pragma unroll
        for (int r = 0; r < 4; r++) {
          int grow = row0 + r;
          float2 cv = cs[(size_t)(grow & 2047) * 32 + d];
          float xl = (lo[r] + blo) * qs, xh = (hi[r] + bhi) * qs;
          Out[(size_t)grow * DD + gcol_lo] = f2bf(xl * cv.x - xh * cv.y);
          Out[(size_t)grow * DD + gcol_hi] = f2bf(xh * cv.x + xl * cv.y);
        }
      }
    }
  }
}

// ---- flash attention v15: v14 q-split + 64-key tiles (half the barriers) ----
// r12 diagnosis: 660 cy/tile budget vs ~45 cy MFMA — the per-tile
// vmcnt(0)+syncthreads drain (64x) dominates.  v15 doubles the tile: same
// MFMA/GLL16 per key, 32 barriers, 2x compute window per prefetch.
// Maps are v14's verbatim with [64][64] K and V tiles (f(row)=row&7 both)
// and a [16][64] P strip (same chunk-XOR family); GLL16 linear dest +
// inverse-swizzled global source (rule #21).  LDS 40 KB -> 4 blocks/CU.
__global__ __launch_bounds__(256)
void attn_kernel(
    const unsigned short* __restrict__ Qr, const unsigned short* __restrict__ Kr,
    const unsigned short* __restrict__ VT, float* __restrict__ out) {
  __shared__ __align__(16) unsigned short Klds[2][4096];  // [buf][64k][64d]
  __shared__ __align__(16) unsigned short Vlds[2][4096];  // [buf][64d][64k]
  __shared__ __align__(16) unsigned short Pall[4][1024];  // per-wave [16q][64k]
  int bx = blockIdx.x;             // bx = qt*40 + bh; head pinned to one XCD (40%8==0)
  int bh = bx % 40, qt = bx / 40;
  int b = bh / HH, h = bh % HH;
  int tid = threadIdx.x;
  int lane = tid & 63, w = tid >> 6;
  int c15 = lane & 15, quad = lane >> 4;
  int q0 = qt * 64 + w * 16;       // this wave's 16 q rows

  // Q fragments in registers (A-operand: m=c15, k=quad*8+j per 32-d chunk)
  const unsigned short* Qb = Qr + (size_t)(b * SS + q0 + c15) * DD + h * 64 + quad * 8;
  bf16x8 qf[2];
  qf[0] = *(const bf16x8*)(Qb);
  qf[1] = *(const bf16x8*)(Qb + 32);

  // staging sources (per-thread, inverse-swizzled global column)
  // K: row tid>>3 (of 32/pass), chunk tid&7 of 8B-groups across d=64
  int srow = tid >> 3, sch = tid & 7;
  const unsigned short* Ksrc = Kr + (size_t)(b * SS + srow) * DD + h * 64
                               + ((sch ^ (srow & 7)) * 8);
  // V: d-row tid>>3 (of 32/pass), chunk tid&7 of 8B-groups across k=64
  const unsigned short* Vsrc = VT + (size_t)(bh * 64 + srow) * SS
                               + ((sch ^ (srow & 7)) * 8);
  unsigned short* Pw = &Pall[w][0];

  bf16x8 ones;
#pragma unroll
  for (int i = 0; i < 8; i++) ones[i] = (__bf16)1.0f;

  f32x4 of[4] = {};   // [nio]: O[q=quad*4+r][d=nio*16+c15]
  f32x4 ol = {};      // l[q=quad*4+r] via P*ones

  // prologue: stage tile 0 into buf 0 (2 passes each for 64 rows)
  GLL16(Ksrc,                      &Klds[0][0] + w * 512);
  GLL16(Ksrc + (size_t)32 * DD,    &Klds[0][0] + 2048 + w * 512);
  GLL16(Vsrc,                      &Vlds[0][0] + w * 512);
  GLL16(Vsrc + (size_t)32 * SS,    &Vlds[0][0] + 2048 + w * 512);
  __syncthreads();

  for (int t = 0; t < 32; t++) {
    int buf = t & 1;
    if (t + 1 < 32) {   // prefetch next 64-key tile into the other buffer
      const unsigned short* Kt = Ksrc + (size_t)((t + 1) * 64) * DD;
      const unsigned short* Vt = Vsrc + (t + 1) * 64;
      GLL16(Kt,                   &Klds[buf ^ 1][0] + w * 512);
      GLL16(Kt + (size_t)32 * DD, &Klds[buf ^ 1][0] + 2048 + w * 512);
      GLL16(Vt,                   &Vlds[buf ^ 1][0] + w * 512);
      GLL16(Vt + (size_t)32 * SS, &Vlds[buf ^ 1][0] + 2048 + w * 512);
    }
    const unsigned short* Kb = &Klds[buf][0];
    const unsigned short* Vb = &Vlds[buf][0];

    // QK^T: S[16q x 64k]
    f32x4 sc[4] = {};
#pragma unroll
    for (int kc = 0; kc < 2; kc++)
#pragma unroll
      for (int ni = 0; ni < 4; ni++) {
        int R = ni * 16 + c15;
        bf16x8 kf = *(const bf16x8*)(Kb + R * 64 + (((kc * 4 + quad) ^ (R & 7)) * 8));
        sc[ni] = __builtin_amdgcn_mfma_f32_16x16x32_bf16(qf[kc], kf, sc[ni], 0, 0, 0);
      }

    // exp2 + pack into this wave's P strip (swizzled, rows 128B)
#pragma unroll
    for (int ni = 0; ni < 4; ni++)
#pragma unroll
      for (int r = 0; r < 4; r++) {
        unsigned u = f2u(__builtin_amdgcn_exp2f(sc[ni][r]));
        int q = quad * 4 + r;
        Pw[q * 64 + (((ni * 2 + (c15 >> 3)) ^ (q & 7)) * 8) + (c15 & 7)] =
            (unsigned short)(u >> 16);
      }

    // PV over both 32-key halves
#pragma unroll
    for (int kb = 0; kb < 2; kb++) {
      bf16x8 pf = *(const bf16x8*)(Pw + c15 * 64 + (((kb * 4 + quad) ^ (c15 & 7)) * 8));
#pragma unroll
      for (int nio = 0; nio < 4; nio++) {
        int R = nio * 16 + c15;
        bf16x8 vf = *(const bf16x8*)(Vb + R * 64 + (((kb * 4 + quad) ^ (R & 7)) * 8));
        of[nio] = __builtin_amdgcn_mfma_f32_16x16x32_bf16(pf, vf, of[nio], 0, 0, 0);
      }
      ol = __builtin_amdgcn_mfma_f32_16x16x32_bf16(pf, ones, ol, 0, 0, 0);
    }

    __syncthreads();   // drains prefetch; guards buf reuse (32 total)
  }

  // epilogue: direct write — each wave owns its 16 q rows end-to-end
#pragma unroll
  for (int r = 0; r < 4; r++) {
    float invl = 1.0f / ol[r];
    float* op = out + (size_t)(b * SS + q0 + quad * 4 + r) * DD + h * 64 + c15;
#pragma unroll
    for (int nio = 0; nio < 4; nio++)
      op[nio * 16] = of[nio][r] * invl;
  }
}

extern "C" void kernel_launch(void* const* d_in, const int* in_sizes, int n_in,
                              void* d_out, int out_size, void* d_ws, size_t ws_size,
                              hipStream_t stream) {
  (void)in_sizes; (void)n_in; (void)out_size; (void)ws_size;
  const float* X  = (const float*)d_in[0];
  const float* Wq = (const float*)d_in[1];
  const float* bq = (const float*)d_in[2];
  const float* Wk = (const float*)d_in[3];
  const float* bk = (const float*)d_in[4];
  const float* Wv = (const float*)d_in[5];
  const float* bv = (const float*)d_in[6];
  char* ws = (char*)d_ws;
  unsigned short* Xb  = (unsigned short*)(ws);                 // 4096x1280 bf16
  unsigned short* WT  = (unsigned short*)(ws + 10485760);      // 3x1280x1280 bf16 (transposed)
  unsigned short* Qr  = (unsigned short*)(ws + 20316160);      // 4096x1280 bf16 (rotary'd, scaled)
  unsigned short* Kr  = (unsigned short*)(ws + 30801920);      // 4096x1280 bf16 (rotary'd)
  unsigned short* VTt = (unsigned short*)(ws + 41287680);      // [40][64][2048] bf16
  float2* cstab       = (float2*)(ws + 51773440);              // 2048x32 float2
  hipLaunchKernelGGL(prep_kernel, dim3(1584), dim3(256), 0, stream, X, Wq, Wk, Wv, Xb, WT, cstab);
  hipLaunchKernelGGL(qkv_gemm_kernel, dim3(960), dim3(256), 0, stream, Xb, WT, bq, bk, bv, cstab, Qr, Kr, VTt);
  hipLaunchKernelGGL(attn_kernel, dim3(1280), dim3(256), 0, stream, Qr, Kr, VTt, (float*)d_out);
}

// Round 14
// 228.321 us; speedup vs baseline: 1.0759x; 1.0759x over previous
//
#include <hip/hip_runtime.h>

#define DD 1280
#define SS 2048
#define HH 20

typedef __bf16 bf16x8 __attribute__((ext_vector_type(8)));
typedef float f32x4 __attribute__((ext_vector_type(4)));

typedef __attribute__((address_space(3))) unsigned int lds_uint;
typedef __attribute__((address_space(1))) unsigned int glb_uint;
#define GLL16(g, l) __builtin_amdgcn_global_load_lds((const glb_uint*)(g), (lds_uint*)(l), 16, 0, 0)

__device__ __forceinline__ unsigned short f2bf(float f) {
  union { float f; unsigned u; } v; v.f = f;
  unsigned r = v.u + 0x7fffu + ((v.u >> 16) & 1u);
  return (unsigned short)(r >> 16);
}
__device__ __forceinline__ unsigned f2u(float f) {
  union { float f; unsigned u; } v; v.f = f; return v.u;
}
__device__ __forceinline__ unsigned pk2(float lo, float hi) {
  return ((unsigned)f2bf(hi) << 16) | (unsigned)f2bf(lo);
}

// ---- prep v3 (frozen) ----
__global__ __launch_bounds__(256) void prep_kernel(
    const float* __restrict__ X, const float* __restrict__ Wq,
    const float* __restrict__ Wk, const float* __restrict__ Wv,
    unsigned short* __restrict__ Xb, unsigned short* __restrict__ WT,
    float2* __restrict__ cs) {
  __shared__ __align__(8) unsigned short tile[64][68];
  int bid = blockIdx.x, tid = threadIdx.x;
  if (bid < 320) {
#pragma unroll
    for (int it = 0; it < 8; it++) {
      size_t base = (size_t)(it * 320 + bid) * 2048 + (size_t)tid * 8;
      const float4* xin = (const float4*)(X + base);
      float4 a = xin[0], c = xin[1];
      uint4 o = make_uint4(pk2(a.x, a.y), pk2(a.z, a.w), pk2(c.x, c.y), pk2(c.z, c.w));
      *(uint4*)(Xb + base) = o;
    }
  } else if (bid < 1520) {
    int wb = bid - 320;           // 3 * 400 tiles of 64x64
    int mat = wb / 400;
    int t = wb % 400;
    int tn = t % 20, tk = t / 20;
    const float* W = (mat == 0) ? Wq : ((mat == 1) ? Wk : Wv);
    int k0 = tk * 64, n0 = tn * 64;
    int r = tid >> 2, cq = tid & 3;   // 256 threads = 64 rows x 4 col-chunks(16)
    const float* src = W + (size_t)(k0 + r) * DD + n0 + cq * 16;
#pragma unroll
    for (int j = 0; j < 4; j++) {
      float4 wv = *(const float4*)(src + j * 4);
      *(ushort4*)&tile[r][cq * 16 + j * 4] =
          make_ushort4(f2bf(wv.x), f2bf(wv.y), f2bf(wv.z), f2bf(wv.w));
    }
    __syncthreads();
    unsigned short* out = WT + (size_t)mat * DD * DD + (size_t)(n0 + r) * DD + k0 + cq * 16;
#pragma unroll
    for (int j = 0; j < 4; j++) {
      ushort4 o = make_ushort4(tile[cq * 16 + j * 4 + 0][r], tile[cq * 16 + j * 4 + 1][r],
                               tile[cq * 16 + j * 4 + 2][r], tile[cq * 16 + j * 4 + 3][r]);
      *(ushort4*)(out + j * 4) = o;
    }
  } else {
    // rotary table: cs[sp][j] = (cos, sin)(sp * 10000^(-j/32)), 2048 x 32
#pragma unroll
    for (int it = 0; it < 4; it++) {
      int idx = (bid - 1520) * 1024 + it * 256 + tid;   // 64 blocks -> 65536 entries
      int sp = idx >> 5, j = idx & 31;
      float invf = exp2f(-(float)j * 0.41524101186092034f);
      float ang = (float)sp * invf;
      cs[idx] = make_float2(cosf(ang), sinf(ang));
    }
  }
}

// ---- QKV GEMM: m97/BK=32 structure + T1 XCD-chunked swizzle (frozen, ~69us) ----
__global__ __launch_bounds__(256) void qkv_gemm_kernel(
    const unsigned short* __restrict__ Xb, const unsigned short* __restrict__ WT,
    const float* __restrict__ bq, const float* __restrict__ bk, const float* __restrict__ bv,
    const float2* __restrict__ cs,
    unsigned short* __restrict__ Qr, unsigned short* __restrict__ Kr,
    unsigned short* __restrict__ VT) {
  __shared__ __align__(16) unsigned short As[128 * 32];
  __shared__ __align__(16) unsigned short Bs[128 * 32];
  int bx0 = blockIdx.x;           // 960 = 8 XCDs * 120
  int bx = (bx0 & 7) * 120 + (bx0 >> 3);   // XCD c works contiguous [c*120, c*120+120)
  int mat = bx / 320;
  int r0 = bx % 320;
  int tm = r0 / 10, tn = r0 % 10;
  int m0 = tm * 128, n0 = tn * 128;
  int tid = threadIdx.x;
  int lane = tid & 63, wave = tid >> 6;
  int c15 = lane & 15, quad = lane >> 4;
  int wm = wave >> 1, wn = wave & 1;
  const unsigned short* Wm = WT + (size_t)mat * DD * DD;

  int rowA = tid >> 2;
  int c8 = (tid & 3) * 8;
  const unsigned short* gA0 = Xb + (size_t)(m0 + rowA) * DD + c8;
  const unsigned short* gA1 = gA0 + (size_t)64 * DD;
  const unsigned short* gB0 = Wm + (size_t)(n0 + rowA) * DD + c8;
  const unsigned short* gB1 = gB0 + (size_t)64 * DD;
  unsigned short* ldsA0 = As + wave * 512;          // rows 0..63
  unsigned short* ldsA1 = As + 2048 + wave * 512;   // rows 64..127
  unsigned short* ldsB0 = Bs + wave * 512;
  unsigned short* ldsB1 = Bs + 2048 + wave * 512;

  f32x4 acc[4][4] = {};

  for (int kk = 0; kk < DD; kk += 32) {
    __syncthreads();
    GLL16(gA0 + kk, ldsA0);
    GLL16(gA1 + kk, ldsA1);
    GLL16(gB0 + kk, ldsB0);
    GLL16(gB1 + kk, ldsB1);
    __syncthreads();
    bf16x8 af[4];
#pragma unroll
    for (int mi = 0; mi < 4; mi++)
      af[mi] = *(const bf16x8*)(As + (wm * 64 + mi * 16 + c15) * 32 + quad * 8);
#pragma unroll
    for (int ni = 0; ni < 4; ni++) {
      bf16x8 bfr = *(const bf16x8*)(Bs + (wn * 64 + ni * 16 + c15) * 32 + quad * 8);
#pragma unroll
      for (int mi = 0; mi < 4; mi++)
        acc[mi][ni] = __builtin_amdgcn_mfma_f32_16x16x32_bf16(af[mi], bfr, acc[mi][ni], 0, 0, 0);
    }
  }

  int growb = m0 + wm * 64;
  int gcolb = n0 + wn * 64;
  if (mat == 2) {
    // V: write transposed VT[(b*H+h)*64+d][s]
#pragma unroll
    for (int mi = 0; mi < 4; mi++) {
      int row0 = growb + mi * 16 + quad * 4;
      int bb_ = row0 >> 11, sp = row0 & 2047;
#pragma unroll
      for (int ni = 0; ni < 4; ni++) {
        int gcol = gcolb + ni * 16 + c15;
        float bias = bv[gcol];
        int hh = gcol >> 6, dd = gcol & 63;
        f32x4 v = acc[mi][ni];
        ushort4 o = make_ushort4(f2bf(v[0] + bias), f2bf(v[1] + bias),
                                 f2bf(v[2] + bias), f2bf(v[3] + bias));
        *(ushort4*)(VT + ((size_t)((bb_ * HH + hh) * 64 + dd)) * SS + sp) = o;
      }
    }
  } else {
    // Q / K: bias + rotary via cs table
    unsigned short* Out = (mat == 0) ? Qr : Kr;
    const float* bias = (mat == 0) ? bq : bk;
    float qs = (mat == 0) ? 0.18033688011112042f : 1.0f;  // 0.125*log2(e) for Q
#pragma unroll
    for (int mi = 0; mi < 4; mi++) {
      int row0 = growb + mi * 16 + quad * 4;
#pragma unroll
      for (int ni = 0; ni < 2; ni++) {
        int gcol_lo = gcolb + ni * 16 + c15;      // d in [0,32) within head
        int gcol_hi = gcol_lo + 32;
        float blo = bias[gcol_lo], bhi = bias[gcol_hi];
        int d = ni * 16 + c15;
        f32x4 lo = acc[mi][ni], hi = acc[mi][ni + 2];
#pragma unroll
        for (int r = 0; r < 4; r++) {
          int grow = row0 + r;
          float2 cv = cs[(size_t)(grow & 2047) * 32 + d];
          float xl = (lo[r] + blo) * qs, xh = (hi[r] + bhi) * qs;
          Out[(size_t)grow * DD + gcol_lo] = f2bf(xl * cv.x - xh * cv.y);
          Out[(size_t)grow * DD + gcol_hi] = f2bf(xh * cv.x + xl * cv.y);
        }
      }
    }
  }
}

// ---- flash attention v16: v14 q-split + triple-buffer + counted vmcnt (T4) ----
// r13: v15's 64-key tile regressed (LDS 40KB -> occ 29%).  v14's stall is the
// per-iter vmcnt(0) drain: the prefetch issued at iter-top is drained at the
// SAME iter's __syncthreads — only one compute phase covers the L2 latency.
// v16: tile n lives in buf[n%3]; prefetch issued TWO tiles ahead; end-of-iter
// sync = s_waitcnt vmcnt(2) (drain t+1's 2 loads, leave t+2's in flight) +
// raw s_barrier + sched_barrier(0) (rule #18).  N=2 per T4 formula (2 loads/
// tile x 1 tile ahead).  Pattern precedent: m201 8-phase counted-vmcnt
// template (refcheck'd).  WAR on buffer overwrite == v14's argument (writes
// issued post-barrier, reads pre-barrier).  Compute phase byte-identical to
// v14.  LDS 28 KB -> 5 blocks/CU.
__global__ __launch_bounds__(256)
void attn_kernel(
    const unsigned short* __restrict__ Qr, const unsigned short* __restrict__ Kr,
    const unsigned short* __restrict__ VT, float* __restrict__ out) {
  __shared__ __align__(16) unsigned short Klds[3][2048];  // [buf][32k][64d]
  __shared__ __align__(16) unsigned short Vlds[3][2048];  // [buf][64d][32k]
  __shared__ __align__(16) unsigned short Pall[4][512];   // per-wave [16q][32k]
  int bx = blockIdx.x;             // bx = qt*40 + bh; head pinned to one XCD (40%8==0)
  int bh = bx % 40, qt = bx / 40;
  int b = bh / HH, h = bh % HH;
  int tid = threadIdx.x;
  int lane = tid & 63, w = tid >> 6;
  int c15 = lane & 15, quad = lane >> 4;
  int q0 = qt * 64 + w * 16;       // this wave's 16 q rows

  // Q fragments in registers (A-operand: m=c15, k=quad*8+j per 32-d chunk)
  const unsigned short* Qb = Qr + (size_t)(b * SS + q0 + c15) * DD + h * 64 + quad * 8;
  bf16x8 qf[2];
  qf[0] = *(const bf16x8*)(Qb);
  qf[1] = *(const bf16x8*)(Qb + 32);

  // staging sources (per-thread, inverse-swizzled global column)
  int krow = tid >> 3, kch = tid & 7;          // K: 32 rows x 8 chunks
  const unsigned short* Ksrc = Kr + (size_t)(b * SS + krow) * DD + h * 64
                               + ((kch ^ (krow & 7)) * 8);
  int vrow = tid >> 2, vch = tid & 3;          // V: 64 rows x 4 chunks
  const unsigned short* Vsrc = VT + (size_t)(bh * 64 + vrow) * SS
                               + ((vch ^ ((vrow >> 1) & 3)) * 8);
  unsigned short* Pw = &Pall[w][0];

  bf16x8 ones;
#pragma unroll
  for (int i = 0; i < 8; i++) ones[i] = (__bf16)1.0f;

  f32x4 of[4] = {};   // [nio]: O[q=quad*4+r][d=nio*16+c15]
  f32x4 ol = {};      // l[q=quad*4+r] via P*ones

  // prologue: stage tile 0 -> buf0, tile 1 -> buf1; wait tile 0 only
  GLL16(Ksrc,                    &Klds[0][0] + w * 512);
  GLL16(Vsrc,                    &Vlds[0][0] + w * 512);
  GLL16(Ksrc + (size_t)32 * DD,  &Klds[1][0] + w * 512);
  GLL16(Vsrc + 32,               &Vlds[1][0] + w * 512);
  asm volatile("s_waitcnt vmcnt(2)" ::: "memory");
  __builtin_amdgcn_sched_barrier(0);
  __builtin_amdgcn_s_barrier();

  for (int t = 0; t < 64; t++) {
    int cur = t % 3;
    if (t + 2 < 64) {   // prefetch tile t+2 (2 compute phases to land)
      int nxt = (t + 2) % 3;
      GLL16(Ksrc + (size_t)((t + 2) * 32) * DD, &Klds[nxt][0] + w * 512);
      GLL16(Vsrc + (t + 2) * 32,                &Vlds[nxt][0] + w * 512);
    }
    const unsigned short* Kb = &Klds[cur][0];
    const unsigned short* Vb = &Vlds[cur][0];

    // QK^T: S[16q x 32k]
    f32x4 sc[2] = {};
#pragma unroll
    for (int kc = 0; kc < 2; kc++)
#pragma unroll
      for (int ni = 0; ni < 2; ni++) {
        int R = ni * 16 + c15;
        bf16x8 kf = *(const bf16x8*)(Kb + R * 64 + (((kc * 4 + quad) ^ (R & 7)) * 8));
        sc[ni] = __builtin_amdgcn_mfma_f32_16x16x32_bf16(qf[kc], kf, sc[ni], 0, 0, 0);
      }

    // exp2 + pack into this wave's P strip (swizzled)
#pragma unroll
    for (int ni = 0; ni < 2; ni++)
#pragma unroll
      for (int r = 0; r < 4; r++) {
        unsigned u = f2u(__builtin_amdgcn_exp2f(sc[ni][r]));
        int q = quad * 4 + r;
        int sw = (ni * 2 + (c15 >> 3)) ^ ((q >> 1) & 3);
        Pw[q * 32 + sw * 8 + (c15 & 7)] = (unsigned short)(u >> 16);
      }

    // PV: read P as A-frag, V as B-frag (both swizzle-consistent)
    bf16x8 pf = *(const bf16x8*)(Pw + c15 * 32 + ((quad ^ ((c15 >> 1) & 3)) * 8));
#pragma unroll
    for (int nio = 0; nio < 4; nio++) {
      int R = nio * 16 + c15;
      bf16x8 vf = *(const bf16x8*)(Vb + R * 32 + ((quad ^ ((R >> 1) & 3)) * 8));
      of[nio] = __builtin_amdgcn_mfma_f32_16x16x32_bf16(pf, vf, of[nio], 0, 0, 0);
    }
    ol = __builtin_amdgcn_mfma_f32_16x16x32_bf16(pf, ones, ol, 0, 0, 0);

    // counted drain: tile t+1 landed; tile t+2 stays in flight
    if (t + 2 < 64) {
      asm volatile("s_waitcnt vmcnt(2)" ::: "memory");
    } else {
      asm volatile("s_waitcnt vmcnt(0)" ::: "memory");
    }
    __builtin_amdgcn_sched_barrier(0);
    __builtin_amdgcn_s_barrier();
  }

  // epilogue: direct write — each wave owns its 16 q rows end-to-end
#pragma unroll
  for (int r = 0; r < 4; r++) {
    float invl = 1.0f / ol[r];
    float* op = out + (size_t)(b * SS + q0 + quad * 4 + r) * DD + h * 64 + c15;
#pragma unroll
    for (int nio = 0; nio < 4; nio++)
      op[nio * 16] = of[nio][r] * invl;
  }
}

extern "C" void kernel_launch(void* const* d_in, const int* in_sizes, int n_in,
                              void* d_out, int out_size, void* d_ws, size_t ws_size,
                              hipStream_t stream) {
  (void)in_sizes; (void)n_in; (void)out_size; (void)ws_size;
  const float* X  = (const float*)d_in[0];
  const float* Wq = (const float*)d_in[1];
  const float* bq = (const float*)d_in[2];
  const float* Wk = (const float*)d_in[3];
  const float* bk = (const float*)d_in[4];
  const float* Wv = (const float*)d_in[5];
  const float* bv = (const float*)d_in[6];
  char* ws = (char*)d_ws;
  unsigned short* Xb  = (unsigned short*)(ws);                 // 4096x1280 bf16
  unsigned short* WT  = (unsigned short*)(ws + 10485760);      // 3x1280x1280 bf16 (transposed)
  unsigned short* Qr  = (unsigned short*)(ws + 20316160);      // 4096x1280 bf16 (rotary'd, scaled)
  unsigned short* Kr  = (unsigned short*)(ws + 30801920);      // 4096x1280 bf16 (rotary'd)
  unsigned short* VTt = (unsigned short*)(ws + 41287680);      // [40][64][2048] bf16
  float2* cstab       = (float2*)(ws + 51773440);              // 2048x32 float2
  hipLaunchKernelGGL(prep_kernel, dim3(1584), dim3(256), 0, stream, X, Wq, Wk, Wv, Xb, WT, cstab);
  hipLaunchKernelGGL(qkv_gemm_kernel, dim3(960), dim3(256), 0, stream, Xb, WT, bq, bk, bv, cstab, Qr, Kr, VTt);
  hipLaunchKernelGGL(attn_kernel, dim3(1280), dim3(256), 0, stream, Qr, Kr, VTt, (float*)d_out);
}

// Round 15
// 227.440 us; speedup vs baseline: 1.0800x; 1.0039x over previous
//
#include <hip/hip_runtime.h>

#define DD 1280
#define SS 2048
#define HH 20

typedef __bf16 bf16x8 __attribute__((ext_vector_type(8)));
typedef float f32x4 __attribute__((ext_vector_type(4)));

typedef __attribute__((address_space(3))) unsigned int lds_uint;
typedef __attribute__((address_space(1))) unsigned int glb_uint;
#define GLL16(g, l) __builtin_amdgcn_global_load_lds((const glb_uint*)(g), (lds_uint*)(l), 16, 0, 0)

__device__ __forceinline__ unsigned short f2bf(float f) {
  union { float f; unsigned u; } v; v.f = f;
  unsigned r = v.u + 0x7fffu + ((v.u >> 16) & 1u);
  return (unsigned short)(r >> 16);
}
__device__ __forceinline__ unsigned f2u(float f) {
  union { float f; unsigned u; } v; v.f = f; return v.u;
}
__device__ __forceinline__ float u2f(unsigned x) {
  union { unsigned u; float f; } v; v.u = x; return v.f;
}
__device__ __forceinline__ unsigned pk2(float lo, float hi) {
  return ((unsigned)f2bf(hi) << 16) | (unsigned)f2bf(lo);
}

// ---- prep v3 (frozen) ----
__global__ __launch_bounds__(256) void prep_kernel(
    const float* __restrict__ X, const float* __restrict__ Wq,
    const float* __restrict__ Wk, const float* __restrict__ Wv,
    unsigned short* __restrict__ Xb, unsigned short* __restrict__ WT,
    float2* __restrict__ cs) {
  __shared__ __align__(8) unsigned short tile[64][68];
  int bid = blockIdx.x, tid = threadIdx.x;
  if (bid < 320) {
#pragma unroll
    for (int it = 0; it < 8; it++) {
      size_t base = (size_t)(it * 320 + bid) * 2048 + (size_t)tid * 8;
      const float4* xin = (const float4*)(X + base);
      float4 a = xin[0], c = xin[1];
      uint4 o = make_uint4(pk2(a.x, a.y), pk2(a.z, a.w), pk2(c.x, c.y), pk2(c.z, c.w));
      *(uint4*)(Xb + base) = o;
    }
  } else if (bid < 1520) {
    int wb = bid - 320;           // 3 * 400 tiles of 64x64
    int mat = wb / 400;
    int t = wb % 400;
    int tn = t % 20, tk = t / 20;
    const float* W = (mat == 0) ? Wq : ((mat == 1) ? Wk : Wv);
    int k0 = tk * 64, n0 = tn * 64;
    int r = tid >> 2, cq = tid & 3;   // 256 threads = 64 rows x 4 col-chunks(16)
    const float* src = W + (size_t)(k0 + r) * DD + n0 + cq * 16;
#pragma unroll
    for (int j = 0; j < 4; j++) {
      float4 wv = *(const float4*)(src + j * 4);
      *(ushort4*)&tile[r][cq * 16 + j * 4] =
          make_ushort4(f2bf(wv.x), f2bf(wv.y), f2bf(wv.z), f2bf(wv.w));
    }
    __syncthreads();
    unsigned short* out = WT + (size_t)mat * DD * DD + (size_t)(n0 + r) * DD + k0 + cq * 16;
#pragma unroll
    for (int j = 0; j < 4; j++) {
      ushort4 o = make_ushort4(tile[cq * 16 + j * 4 + 0][r], tile[cq * 16 + j * 4 + 1][r],
                               tile[cq * 16 + j * 4 + 2][r], tile[cq * 16 + j * 4 + 3][r]);
      *(ushort4*)(out + j * 4) = o;
    }
  } else {
    // rotary table: cs[sp][j] = (cos, sin)(sp * 10000^(-j/32)), 2048 x 32
#pragma unroll
    for (int it = 0; it < 4; it++) {
      int idx = (bid - 1520) * 1024 + it * 256 + tid;   // 64 blocks -> 65536 entries
      int sp = idx >> 5, j = idx & 31;
      float invf = exp2f(-(float)j * 0.41524101186092034f);
      float ang = (float)sp * invf;
      cs[idx] = make_float2(cosf(ang), sinf(ang));
    }
  }
}

// ---- QKV GEMM: m97/BK=32 structure + T1 XCD-chunked swizzle (frozen, ~69us) ----
__global__ __launch_bounds__(256) void qkv_gemm_kernel(
    const unsigned short* __restrict__ Xb, const unsigned short* __restrict__ WT,
    const float* __restrict__ bq, const float* __restrict__ bk, const float* __restrict__ bv,
    const float2* __restrict__ cs,
    unsigned short* __restrict__ Qr, unsigned short* __restrict__ Kr,
    unsigned short* __restrict__ VT) {
  __shared__ __align__(16) unsigned short As[128 * 32];
  __shared__ __align__(16) unsigned short Bs[128 * 32];
  int bx0 = blockIdx.x;           // 960 = 8 XCDs * 120
  int bx = (bx0 & 7) * 120 + (bx0 >> 3);   // XCD c works contiguous [c*120, c*120+120)
  int mat = bx / 320;
  int r0 = bx % 320;
  int tm = r0 / 10, tn = r0 % 10;
  int m0 = tm * 128, n0 = tn * 128;
  int tid = threadIdx.x;
  int lane = tid & 63, wave = tid >> 6;
  int c15 = lane & 15, quad = lane >> 4;
  int wm = wave >> 1, wn = wave & 1;
  const unsigned short* Wm = WT + (size_t)mat * DD * DD;

  int rowA = tid >> 2;
  int c8 = (tid & 3) * 8;
  const unsigned short* gA0 = Xb + (size_t)(m0 + rowA) * DD + c8;
  const unsigned short* gA1 = gA0 + (size_t)64 * DD;
  const unsigned short* gB0 = Wm + (size_t)(n0 + rowA) * DD + c8;
  const unsigned short* gB1 = gB0 + (size_t)64 * DD;
  unsigned short* ldsA0 = As + wave * 512;          // rows 0..63
  unsigned short* ldsA1 = As + 2048 + wave * 512;   // rows 64..127
  unsigned short* ldsB0 = Bs + wave * 512;
  unsigned short* ldsB1 = Bs + 2048 + wave * 512;

  f32x4 acc[4][4] = {};

  for (int kk = 0; kk < DD; kk += 32) {
    __syncthreads();
    GLL16(gA0 + kk, ldsA0);
    GLL16(gA1 + kk, ldsA1);
    GLL16(gB0 + kk, ldsB0);
    GLL16(gB1 + kk, ldsB1);
    __syncthreads();
    bf16x8 af[4];
#pragma unroll
    for (int mi = 0; mi < 4; mi++)
      af[mi] = *(const bf16x8*)(As + (wm * 64 + mi * 16 + c15) * 32 + quad * 8);
#pragma unroll
    for (int ni = 0; ni < 4; ni++) {
      bf16x8 bfr = *(const bf16x8*)(Bs + (wn * 64 + ni * 16 + c15) * 32 + quad * 8);
#pragma unroll
      for (int mi = 0; mi < 4; mi++)
        acc[mi][ni] = __builtin_amdgcn_mfma_f32_16x16x32_bf16(af[mi], bfr, acc[mi][ni], 0, 0, 0);
    }
  }

  int growb = m0 + wm * 64;
  int gcolb = n0 + wn * 64;
  if (mat == 2) {
    // V: write transposed VT[(b*H+h)*64+d][s]
#pragma unroll
    for (int mi = 0; mi < 4; mi++) {
      int row0 = growb + mi * 16 + quad * 4;
      int bb_ = row0 >> 11, sp = row0 & 2047;
#pragma unroll
      for (int ni = 0; ni < 4; ni++) {
        int gcol = gcolb + ni * 16 + c15;
        float bias = bv[gcol];
        int hh = gcol >> 6, dd = gcol & 63;
        f32x4 v = acc[mi][ni];
        ushort4 o = make_ushort4(f2bf(v[0] + bias), f2bf(v[1] + bias),
                                 f2bf(v[2] + bias), f2bf(v[3] + bias));
        *(ushort4*)(VT + ((size_t)((bb_ * HH + hh) * 64 + dd)) * SS + sp) = o;
      }
    }
  } else {
    // Q / K: bias + rotary via cs table
    unsigned short* Out = (mat == 0) ? Qr : Kr;
    const float* bias = (mat == 0) ? bq : bk;
    float qs = (mat == 0) ? 0.18033688011112042f : 1.0f;  // 0.125*log2(e) for Q
#pragma unroll
    for (int mi = 0; mi < 4; mi++) {
      int row0 = growb + mi * 16 + quad * 4;
#pragma unroll
      for (int ni = 0; ni < 2; ni++) {
        int gcol_lo = gcolb + ni * 16 + c15;      // d in [0,32) within head
        int gcol_hi = gcol_lo + 32;
        float blo = bias[gcol_lo], bhi = bias[gcol_hi];
        int d = ni * 16 + c15;
        f32x4 lo = acc[mi][ni], hi = acc[mi][ni + 2];
#pragma unroll
        for (int r = 0; r < 4; r++) {
          int grow = row0 + r;
          float2 cv = cs[(size_t)(grow & 2047) * 32 + d];
          float xl = (lo[r] + blo) * qs, xh = (hi[r] + bhi) * qs;
          Out[(size_t)grow * DD + gcol_lo] = f2bf(xl * cv.x - xh * cv.y);
          Out[(size_t)grow * DD + gcol_hi] = f2bf(xh * cv.x + xl * cv.y);
        }
      }
    }
  }
}

// ---- flash attention v17: v16 pipeline + IN-REGISTER P (v11-verified path) ----
// r14: v16 at 82us, MfmaUtil 25 / VALU 32 — remaining per-tile serial chain
// is the P LDS round-trip (8 ds_write -> lgkm -> ds_read, ~150cy inside the
// QK->PV dependency).  v17 transplants the v11-PASSED in-register-P path:
//   * swapped QK^T: mfma(kf, qf) — SAME loads/registers, operands exchanged.
//     S^T C/D: col=c15=q(local), row=quad*4+r=kpos (+16 for sc[1]).
//   * truncation pack (v11-verified bit ops): af elem j <-> kpos
//     rho(quad,j) = j<4 ? 4*quad+j : 16+4*quad+(j-4).
//   * V read with the SAME rho from the swizzled LDS tile: two 8B ushort4 at
//     chunk ((quad>>1)^f(R)) and ((2+(quad>>1))^f(R)), half (quad&1)*4,
//     f(R)=(R>>1)&3  [LDS[R][c]=global[R][c^f(R)] by staging construction].
//   * l = VALU tree of truncated words (numerator-consistent, v11-verified)
//     + quad butterfly (shfl_xor 16,32) + 4 epilogue shfls; ones-MFMA gone.
// Pall deleted: LDS 24.6 KB -> 6 blocks/CU.  Pipeline/barriers = v16 verbatim.
__global__ __launch_bounds__(256)
void attn_kernel(
    const unsigned short* __restrict__ Qr, const unsigned short* __restrict__ Kr,
    const unsigned short* __restrict__ VT, float* __restrict__ out) {
  __shared__ __align__(16) unsigned short Klds[3][2048];  // [buf][32k][64d]
  __shared__ __align__(16) unsigned short Vlds[3][2048];  // [buf][64d][32k]
  int bx = blockIdx.x;             // bx = qt*40 + bh; head pinned to one XCD (40%8==0)
  int bh = bx % 40, qt = bx / 40;
  int b = bh / HH, h = bh % HH;
  int tid = threadIdx.x;
  int lane = tid & 63, w = tid >> 6;
  int c15 = lane & 15, quad = lane >> 4;
  int q0 = qt * 64 + w * 16;       // this wave's 16 q rows

  // Q fragments in registers (lane m/n = c15 = q_local, k = quad*8+j per 32-d chunk)
  const unsigned short* Qb = Qr + (size_t)(b * SS + q0 + c15) * DD + h * 64 + quad * 8;
  bf16x8 qf[2];
  qf[0] = *(const bf16x8*)(Qb);
  qf[1] = *(const bf16x8*)(Qb + 32);

  // staging sources (per-thread, inverse-swizzled global column)
  int krow = tid >> 3, kch = tid & 7;          // K: 32 rows x 8 chunks
  const unsigned short* Ksrc = Kr + (size_t)(b * SS + krow) * DD + h * 64
                               + ((kch ^ (krow & 7)) * 8);
  int vrow = tid >> 2, vch = tid & 3;          // V: 64 rows x 4 chunks
  const unsigned short* Vsrc = VT + (size_t)(bh * 64 + vrow) * SS
                               + ((vch ^ ((vrow >> 1) & 3)) * 8);

  f32x4 of[4] = {};   // [nio]: O[q=quad*4+r][d=nio*16+c15]
  float ol = 0.f;     // this lane's partial l for q=c15 (its 8 kpos per tile)

  // prologue: stage tile 0 -> buf0, tile 1 -> buf1; wait tile 0 only
  GLL16(Ksrc,                    &Klds[0][0] + w * 512);
  GLL16(Vsrc,                    &Vlds[0][0] + w * 512);
  GLL16(Ksrc + (size_t)32 * DD,  &Klds[1][0] + w * 512);
  GLL16(Vsrc + 32,               &Vlds[1][0] + w * 512);
  asm volatile("s_waitcnt vmcnt(2)" ::: "memory");
  __builtin_amdgcn_sched_barrier(0);
  __builtin_amdgcn_s_barrier();

  for (int t = 0; t < 64; t++) {
    int cur = t % 3;
    if (t + 2 < 64) {   // prefetch tile t+2 (2 compute phases to land)
      int nxt = (t + 2) % 3;
      GLL16(Ksrc + (size_t)((t + 2) * 32) * DD, &Klds[nxt][0] + w * 512);
      GLL16(Vsrc + (t + 2) * 32,                &Vlds[nxt][0] + w * 512);
    }
    const unsigned short* Kb = &Klds[cur][0];
    const unsigned short* Vb = &Vlds[cur][0];

    // swapped QK^T: S^T[32k x 16q]; kf is the A operand (same read as v16)
    f32x4 sc[2] = {};
#pragma unroll
    for (int kc = 0; kc < 2; kc++)
#pragma unroll
      for (int ni = 0; ni < 2; ni++) {
        int R = ni * 16 + c15;
        bf16x8 kf = *(const bf16x8*)(Kb + R * 64 + (((kc * 4 + quad) ^ (R & 7)) * 8));
        sc[ni] = __builtin_amdgcn_mfma_f32_16x16x32_bf16(kf, qf[kc], sc[ni], 0, 0, 0);
      }

    // exp2 + truncation pack (v11-verified): lane holds P[rho(quad,j)][q=c15]
    unsigned e0 = f2u(__builtin_amdgcn_exp2f(sc[0][0]));
    unsigned e1 = f2u(__builtin_amdgcn_exp2f(sc[0][1]));
    unsigned e2 = f2u(__builtin_amdgcn_exp2f(sc[0][2]));
    unsigned e3 = f2u(__builtin_amdgcn_exp2f(sc[0][3]));
    unsigned e4 = f2u(__builtin_amdgcn_exp2f(sc[1][0]));
    unsigned e5 = f2u(__builtin_amdgcn_exp2f(sc[1][1]));
    unsigned e6 = f2u(__builtin_amdgcn_exp2f(sc[1][2]));
    unsigned e7 = f2u(__builtin_amdgcn_exp2f(sc[1][3]));
    union { unsigned u[4]; bf16x8 v; } af;
    af.u[0] = (e1 & 0xffff0000u) | (e0 >> 16);
    af.u[1] = (e3 & 0xffff0000u) | (e2 >> 16);
    af.u[2] = (e5 & 0xffff0000u) | (e4 >> 16);
    af.u[3] = (e7 & 0xffff0000u) | (e6 >> 16);
    {
      float s01 = u2f(e0 & 0xffff0000u) + u2f(e1 & 0xffff0000u);
      float s23 = u2f(e2 & 0xffff0000u) + u2f(e3 & 0xffff0000u);
      float s45 = u2f(e4 & 0xffff0000u) + u2f(e5 & 0xffff0000u);
      float s67 = u2f(e6 & 0xffff0000u) + u2f(e7 & 0xffff0000u);
      ol += (s01 + s23) + (s45 + s67);
    }

    // PV: af as A-frag; V read with matching key permutation rho from LDS
#pragma unroll
    for (int nio = 0; nio < 4; nio++) {
      int R = nio * 16 + c15;
      int f = (R >> 1) & 3;
      union { ushort4 s[2]; bf16x8 v; } vf;
      vf.s[0] = *(const ushort4*)(Vb + R * 32 + ((((quad >> 1)) ^ f) * 8) + (quad & 1) * 4);
      vf.s[1] = *(const ushort4*)(Vb + R * 32 + (((2 + (quad >> 1)) ^ f) * 8) + (quad & 1) * 4);
      of[nio] = __builtin_amdgcn_mfma_f32_16x16x32_bf16(af.v, vf.v, of[nio], 0, 0, 0);
    }

    // counted drain: tile t+1 landed; tile t+2 stays in flight
    if (t + 2 < 64) {
      asm volatile("s_waitcnt vmcnt(2)" ::: "memory");
    } else {
      asm volatile("s_waitcnt vmcnt(0)" ::: "memory");
    }
    __builtin_amdgcn_sched_barrier(0);
    __builtin_amdgcn_s_barrier();
  }

  // l: butterfly over quad bits -> every lane holds total l for q = c15
  float lt = ol;
  lt += __shfl_xor(lt, 16);
  lt += __shfl_xor(lt, 32);

  // epilogue: direct write; l for row q=quad*4+r fetched from lane (quad*4+r)
#pragma unroll
  for (int r = 0; r < 4; r++) {
    float lq = __shfl(lt, quad * 4 + r);
    float invl = 1.0f / lq;
    float* op = out + (size_t)(b * SS + q0 + quad * 4 + r) * DD + h * 64 + c15;
#pragma unroll
    for (int nio = 0; nio < 4; nio++)
      op[nio * 16] = of[nio][r] * invl;
  }
}

extern "C" void kernel_launch(void* const* d_in, const int* in_sizes, int n_in,
                              void* d_out, int out_size, void* d_ws, size_t ws_size,
                              hipStream_t stream) {
  (void)in_sizes; (void)n_in; (void)out_size; (void)ws_size;
  const float* X  = (const float*)d_in[0];
  const float* Wq = (const float*)d_in[1];
  const float* bq = (const float*)d_in[2];
  const float* Wk = (const float*)d_in[3];
  const float* bk = (const float*)d_in[4];
  const float* Wv = (const float*)d_in[5];
  const float* bv = (const float*)d_in[6];
  char* ws = (char*)d_ws;
  unsigned short* Xb  = (unsigned short*)(ws);                 // 4096x1280 bf16
  unsigned short* WT  = (unsigned short*)(ws + 10485760);      // 3x1280x1280 bf16 (transposed)
  unsigned short* Qr  = (unsigned short*)(ws + 20316160);      // 4096x1280 bf16 (rotary'd, scaled)
  unsigned short* Kr  = (unsigned short*)(ws + 30801920);      // 4096x1280 bf16 (rotary'd)
  unsigned short* VTt = (unsigned short*)(ws + 41287680);      // [40][64][2048] bf16
  float2* cstab       = (float2*)(ws + 51773440);              // 2048x32 float2
  hipLaunchKernelGGL(prep_kernel, dim3(1584), dim3(256), 0, stream, X, Wq, Wk, Wv, Xb, WT, cstab);
  hipLaunchKernelGGL(qkv_gemm_kernel, dim3(960), dim3(256), 0, stream, Xb, WT, bq, bk, bv, cstab, Qr, Kr, VTt);
  hipLaunchKernelGGL(attn_kernel, dim3(1280), dim3(256), 0, stream, Qr, Kr, VTt, (float*)d_out);
}